// Round 1
// 1248.658 us; speedup vs baseline: 1.1595x; 1.1595x over previous
//
#include <hip/hip_runtime.h>
#include <math.h>

// ---------------------------------------------------------------------------
// Santacoder MQA prefill: B=2, S=1024, D=2048, H=16, HD=128, L=2, FF=8192
// R3: fc/mp/proj GEMMs moved to 256x256 tile, BK=64, 512-thread pipelined
// kernel (counted vmcnt(8), raw s_barrier, XOR-swizzled LDS via pre-swizzled
// global_load_lds source, setprio around MFMA clusters). qkv stays on the
// 128^2 split-K kernel (N=2304 doesn't tile to 256^2 at full occupancy).
// proj partials (split-K x4) now land in pm (free at that point), reduced by
// the existing 4-way ln_red.
// ---------------------------------------------------------------------------

typedef __bf16 bf16x8 __attribute__((ext_vector_type(8)));
typedef __bf16 bf16x4v __attribute__((ext_vector_type(4)));
typedef float floatx4 __attribute__((ext_vector_type(4)));

typedef const __attribute__((address_space(1))) void* gas_ptr;
typedef __attribute__((address_space(3))) void* las_ptr;

__device__ __forceinline__ void glds16(const __bf16* g, __bf16* l) {
  __builtin_amdgcn_global_load_lds((gas_ptr)g, (las_ptr)l, 16, 0, 0);
}

__device__ __forceinline__ float gelu_tanh(float x) {
  float u = 0.7978845608028654f * (x + 0.044715f * x * x * x);
  return 0.5f * x * (1.f + tanhf(u));
}

// ---------------------------------------------------------------------------
// Embedding: h[t] = wte[ids[t]] + wpe[pos[t]]
// ---------------------------------------------------------------------------
__global__ __launch_bounds__(256)
void embed_kernel(const int* __restrict__ ids, const int* __restrict__ pos,
                  const float* __restrict__ wte, const float* __restrict__ wpe,
                  float* __restrict__ out)
{
  const int t = blockIdx.x;
  const int id = ids[t], pp = pos[t];
  const float4* a = (const float4*)(wte + (size_t)id * 2048);
  const float4* b = (const float4*)(wpe + (size_t)pp * 2048);
  float4* o = (float4*)(out + (size_t)t * 2048);
#pragma unroll
  for (int j = 0; j < 2; j++) {
    int i = threadIdx.x + j * 256;
    float4 x = a[i], y = b[i];
    x.x += y.x; x.y += y.y; x.z += y.z; x.w += y.w;
    o[i] = x;
  }
}

// ---------------------------------------------------------------------------
// Weight convert + transpose: in f32 [K][N] -> out bf16 [N][K]
// ---------------------------------------------------------------------------
__global__ __launch_bounds__(256)
void wcvt_kernel(const float* __restrict__ in, __bf16* __restrict__ out,
                 const int K, const int N)
{
  __shared__ __bf16 tile[32][36];
  const int n0 = blockIdx.x * 32, k0 = blockIdx.y * 32;
  const int t = threadIdx.x;
  const int r = t >> 3, c = (t & 7) * 4;
  const float4 v = *(const float4*)&in[(size_t)(k0 + r) * N + n0 + c];
  tile[r][c + 0] = (__bf16)v.x;
  tile[r][c + 1] = (__bf16)v.y;
  tile[r][c + 2] = (__bf16)v.z;
  tile[r][c + 3] = (__bf16)v.w;
  __syncthreads();
  bf16x4v w;
  w.x = tile[c + 0][r]; w.y = tile[c + 1][r];
  w.z = tile[c + 2][r]; w.w = tile[c + 3][r];
  *(bf16x4v*)&out[(size_t)(n0 + r) * K + k0 + c] = w;
}

// ---------------------------------------------------------------------------
// V transpose: qkv[:, 2176:2304] bf16 -> vT [B][128][1024]
// ---------------------------------------------------------------------------
__global__ __launch_bounds__(256)
void vtr_kernel(const __bf16* __restrict__ qkvb, __bf16* __restrict__ vT)
{
  __shared__ __bf16 tile[32][36];
  const int d0 = blockIdx.x * 32, s0 = blockIdx.y * 32, b = blockIdx.z;
  const int t = threadIdx.x;
  const int r = t >> 3, c = (t & 7) * 4;
  bf16x4v v = *(const bf16x4v*)&qkvb[(size_t)(b * 1024 + s0 + r) * 2304 + 2176 + d0 + c];
  tile[r][c + 0] = v.x; tile[r][c + 1] = v.y;
  tile[r][c + 2] = v.z; tile[r][c + 3] = v.w;
  __syncthreads();
  bf16x4v w;
  w.x = tile[c + 0][r]; w.y = tile[c + 1][r];
  w.z = tile[c + 2][r]; w.w = tile[c + 3][r];
  *(bf16x4v*)&vT[(size_t)b * 131072 + (size_t)(d0 + r) * 1024 + s0 + c] = w;
}

// ---------------------------------------------------------------------------
// Fused partial-sum reduce + bias + residual-add + LayerNorm.
// x = p0 [+p1 +p2 +p3] [+cbias] [+resid]; res_out=x (opt); LN(x) -> out_b/out_f
// ---------------------------------------------------------------------------
__global__ __launch_bounds__(256)
void ln_red_kernel(const float* __restrict__ p0, const float* __restrict__ p1,
                   const float* __restrict__ p2, const float* __restrict__ p3,
                   const float* __restrict__ cbias, const float* __restrict__ resid,
                   float* __restrict__ res_out, __bf16* __restrict__ out_b,
                   float* __restrict__ out_f,
                   const float* __restrict__ gw, const float* __restrict__ gb)
{
  const int row = blockIdx.x;
  const int tid = threadIdx.x;
  const size_t base = (size_t)row * 2048;
  float4 v[2];
  float s = 0.f, sq = 0.f;
#pragma unroll
  for (int j = 0; j < 2; j++) {
    const int idx = tid + j * 256;
    float4 a = ((const float4*)(p0 + base))[idx];
    if (p1) { float4 t = ((const float4*)(p1 + base))[idx];
      a.x += t.x; a.y += t.y; a.z += t.z; a.w += t.w; }
    if (p2) { float4 t = ((const float4*)(p2 + base))[idx];
      a.x += t.x; a.y += t.y; a.z += t.z; a.w += t.w; }
    if (p3) { float4 t = ((const float4*)(p3 + base))[idx];
      a.x += t.x; a.y += t.y; a.z += t.z; a.w += t.w; }
    if (cbias) { float4 t = ((const float4*)cbias)[idx];
      a.x += t.x; a.y += t.y; a.z += t.z; a.w += t.w; }
    if (resid) { float4 t = ((const float4*)(resid + base))[idx];
      a.x += t.x; a.y += t.y; a.z += t.z; a.w += t.w; }
    if (res_out) ((float4*)(res_out + base))[idx] = a;
    v[j] = a;
    s  += a.x + a.y + a.z + a.w;
    sq += a.x * a.x + a.y * a.y + a.z * a.z + a.w * a.w;
  }
  __shared__ float rs[4], rq[4];
  __shared__ float sh_stats[2];
#pragma unroll
  for (int off = 32; off > 0; off >>= 1) {
    s  += __shfl_down(s, off);
    sq += __shfl_down(sq, off);
  }
  const int lane = tid & 63, wave = tid >> 6;
  if (lane == 0) { rs[wave] = s; rq[wave] = sq; }
  __syncthreads();
  if (tid == 0) {
    float S = rs[0] + rs[1] + rs[2] + rs[3];
    float Q = rq[0] + rq[1] + rq[2] + rq[3];
    float mean = S * (1.f / 2048.f);
    float var  = Q * (1.f / 2048.f) - mean * mean;
    sh_stats[0] = mean;
    sh_stats[1] = rsqrtf(var + 1e-5f);
  }
  __syncthreads();
  const float mean = sh_stats[0], rstd = sh_stats[1];
#pragma unroll
  for (int j = 0; j < 2; j++) {
    const int idx = tid + j * 256;
    float4 a = v[j];
    float4 g4 = ((const float4*)gw)[idx];
    float4 b4 = ((const float4*)gb)[idx];
    float y0 = (a.x - mean) * rstd * g4.x + b4.x;
    float y1 = (a.y - mean) * rstd * g4.y + b4.y;
    float y2 = (a.z - mean) * rstd * g4.z + b4.z;
    float y3 = (a.w - mean) * rstd * g4.w + b4.w;
    if (out_b) {
      bf16x4v w;
      w.x = (__bf16)y0; w.y = (__bf16)y1; w.z = (__bf16)y2; w.w = (__bf16)y3;
      *(bf16x4v*)&out_b[base + (size_t)idx * 4] = w;
    }
    if (out_f) {
      float4 w; w.x = y0; w.y = y1; w.z = y2; w.w = y3;
      ((float4*)(out_f + base))[idx] = w;
    }
  }
}

// ---------------------------------------------------------------------------
// qkv split-K reduce: out_bf16 = p0 + p1 + bias   (N = 2304)
// ---------------------------------------------------------------------------
__global__ __launch_bounds__(256)
void bias_red_bf16_kernel(const float* __restrict__ p0, const float* __restrict__ p1,
                          const float* __restrict__ bias, __bf16* __restrict__ out)
{
  const size_t i = ((size_t)blockIdx.x * 256 + threadIdx.x) * 4;
  const int col = (int)(i % 2304);
  float4 a = *(const float4*)(p0 + i);
  const float4 b = *(const float4*)(p1 + i);
  const float4 c = *(const float4*)(bias + col);
  bf16x4v w;
  w.x = (__bf16)(a.x + b.x + c.x);
  w.y = (__bf16)(a.y + b.y + c.y);
  w.z = (__bf16)(a.z + b.z + c.z);
  w.w = (__bf16)(a.w + b.w + c.w);
  *(bf16x4v*)(out + i) = w;
}

// ---------------------------------------------------------------------------
// GEMM (legacy 128^2, kept for qkv): C = A[M][K] * Bt[N][K]^T (+bias).
// 128x128 tile, BK=32, 4 waves, global_load_lds w16. blockIdx.z = K-split.
// MODE 3: f32 partial (no bias), output offset by split*M*N.
// ---------------------------------------------------------------------------
template<int MODE>
__global__ __launch_bounds__(256)
void gemm_bt_kernel(const __bf16* __restrict__ A, const __bf16* __restrict__ Bt,
                    const float* __restrict__ bias, void* __restrict__ Cout,
                    const int M, const int N, const int K, const int Kper)
{
  __shared__ __bf16 As[128 * 32];
  __shared__ __bf16 Bs[128 * 32];
  const int tid  = threadIdx.x;
  const int lane = tid & 63;
  const int wave = tid >> 6;
  const int col  = lane & 15;
  const int quad = lane >> 4;
  const int m0 = blockIdx.y * 128;
  const int n0 = blockIdx.x * 128;
  const int wm = (wave & 1) * 64;
  const int wn = (wave >> 1) * 64;
  const int s  = blockIdx.z;
  floatx4 acc[4][4] = {};

  const int srow = tid >> 2;
  const int scol = (tid & 3) * 8;
  const __bf16* Ag = A  + (size_t)s * Kper + (size_t)(m0 + srow) * K + scol;
  const __bf16* Bg = Bt + (size_t)s * Kper + (size_t)(n0 + srow) * K + scol;
  const size_t rowskip = (size_t)64 * K;

  for (int k0 = 0; k0 < Kper; k0 += 32) {
    glds16(Ag + k0,           As + tid * 8);
    glds16(Ag + k0 + rowskip, As + 2048 + tid * 8);
    glds16(Bg + k0,           Bs + tid * 8);
    glds16(Bg + k0 + rowskip, Bs + 2048 + tid * 8);
    __syncthreads();
    bf16x8 af[4], bf[4];
#pragma unroll
    for (int mi = 0; mi < 4; mi++)
      af[mi] = *(const bf16x8*)&As[(wm + mi * 16 + col) * 32 + quad * 8];
#pragma unroll
    for (int ni = 0; ni < 4; ni++)
      bf[ni] = *(const bf16x8*)&Bs[(wn + ni * 16 + col) * 32 + quad * 8];
#pragma unroll
    for (int mi = 0; mi < 4; mi++)
#pragma unroll
      for (int ni = 0; ni < 4; ni++)
        acc[mi][ni] = __builtin_amdgcn_mfma_f32_16x16x32_bf16(af[mi], bf[ni], acc[mi][ni], 0, 0, 0);
    __syncthreads();
  }

  float* Cp = (MODE == 3) ? ((float*)Cout + (size_t)s * M * N) : (float*)Cout;
#pragma unroll
  for (int ni = 0; ni < 4; ni++) {
    const int cc = n0 + wn + ni * 16 + col;
    const float bv = (MODE == 3) ? 0.f : bias[cc];
#pragma unroll
    for (int mi = 0; mi < 4; mi++) {
#pragma unroll
      for (int r = 0; r < 4; r++) {
        const int rr = m0 + wm + mi * 16 + quad * 4 + r;
        float v = acc[mi][ni][r] + bv;
        if constexpr (MODE == 2) v = gelu_tanh(v);
        if constexpr (MODE == 0 || MODE == 3)
          Cp[(size_t)rr * N + cc] = v;
        else
          ((__bf16*)Cout)[(size_t)rr * N + cc] = (__bf16)v;
      }
    }
  }
}

// ---------------------------------------------------------------------------
// R3 GEMM: 256x256 tile, BK=64, 512 threads (2M x 4N waves), double-buffered
// 128 KiB LDS, counted-vmcnt pipeline (T3+T4), XOR-swizzled LDS (T2, rule
// #21: linear glds dest + inverse-swizzled GLOBAL source + swizzled read),
// setprio around MFMA clusters (T5). 1 block/CU (LDS-pinned).
//   MODE 2: bf16 out + bias + gelu;  MODE 3: f32 partial at split*M*N.
// Requires: M%256==0, N%256==0, Kper%64==0, Kper/64 >= 2.
// Ledger: prologue stages tiles 0,1 -> vmcnt(8)+bar (tile0 resident).
// iter t: read all frags from slot t&1 -> MFMA half1 -> lgkmcnt(0)+bar (slot
// free) -> stage tile t+2 into slot -> MFMA half2 -> vmcnt(8)+bar (tile t+1
// resident). Tail (t>=NT-2): no stage; vmcnt(0) before last-tile iter.
// ---------------------------------------------------------------------------
template<int MODE>
__global__ __launch_bounds__(512, 2)
void gemm256_kernel(const __bf16* __restrict__ A, const __bf16* __restrict__ Bt,
                    const float* __restrict__ bias, void* __restrict__ Cout,
                    const int M, const int N, const int K, const int Kper)
{
  __shared__ alignas(16) __bf16 sm[65536];  // [slot][A(16384)|B(16384)] = 128 KiB
  const int tid  = threadIdx.x;
  const int lane = tid & 63;
  const int wave = tid >> 6;
  const int col  = lane & 15;
  const int quad = lane >> 4;
  const int wm = (wave >> 2) * 128;   // wave row-offset (2 waves in M)
  const int wn = (wave & 3) * 64;     // wave col-offset (4 waves in N)
  const int m0 = blockIdx.y * 256;
  const int n0 = blockIdx.x * 256;
  const int ksplit = blockIdx.z;

  const __bf16* Ag = A  + (size_t)m0 * K + (size_t)ksplit * Kper;
  const __bf16* Bg = Bt + (size_t)n0 * K + (size_t)ksplit * Kper;

  // staging: thread tid covers LDS 16B slot (row = i*64 + tid>>3,
  // slot8 = tid&7). Source column pre-swizzled: c8 = (tid&7) ^ (row&7).
  const int sr = tid >> 3;                       // 0..63 rows per issue
  const int sc = (((tid & 7) ^ (sr & 7)) * 8);   // swizzled source col (elems)
  const int ld = tid * 8;                        // linear LDS dest (elems)

  // read side: frag at k-slot k8=(ks<<2)|quad lives at LDS slot8 k8^(row&7);
  // row&7 == col&7 for every fragment row (wm,mi*16,wn,ni*16 are 0 mod 8).
  const int roff0 = (((0 | quad) ^ (col & 7)) * 8);
  const int roff1 = (((4 | quad) ^ (col & 7)) * 8);

  const int NT = Kper / 64;

  auto stage = [&](int t, int slot) {
    __bf16* dA = sm + slot * 32768;
    __bf16* dB = dA + 16384;
    const __bf16* gA = Ag + t * 64;
    const __bf16* gB = Bg + t * 64;
#pragma unroll
    for (int i = 0; i < 4; i++)
      glds16(gA + (size_t)(i * 64 + sr) * K + sc, dA + i * 4096 + ld);
#pragma unroll
    for (int i = 0; i < 4; i++)
      glds16(gB + (size_t)(i * 64 + sr) * K + sc, dB + i * 4096 + ld);
  };

  floatx4 acc[8][4] = {};

  // prologue
  stage(0, 0);
  stage(1, 1);
  asm volatile("s_waitcnt vmcnt(8)" ::: "memory");
  __builtin_amdgcn_s_barrier();
  __builtin_amdgcn_sched_barrier(0);

  for (int t = 0; t < NT; t++) {
    const int slot = t & 1;
    const __bf16* As = sm + slot * 32768;
    const __bf16* Bs = As + 16384;
    bf16x8 af[8][2], bf[4][2];
#pragma unroll
    for (int ni = 0; ni < 4; ni++) {
      bf[ni][0] = *(const bf16x8*)&Bs[(wn + ni * 16 + col) * 64 + roff0];
      bf[ni][1] = *(const bf16x8*)&Bs[(wn + ni * 16 + col) * 64 + roff1];
    }
#pragma unroll
    for (int mi = 0; mi < 4; mi++) {
      af[mi][0] = *(const bf16x8*)&As[(wm + mi * 16 + col) * 64 + roff0];
      af[mi][1] = *(const bf16x8*)&As[(wm + mi * 16 + col) * 64 + roff1];
    }
    // half 1: mi 0..3 (compiler inserts fine-grained lgkmcnt for frag deps)
    __builtin_amdgcn_s_setprio(1);
#pragma unroll
    for (int mi = 0; mi < 4; mi++)
#pragma unroll
      for (int ni = 0; ni < 4; ni++)
#pragma unroll
        for (int ks = 0; ks < 2; ks++)
          acc[mi][ni] = __builtin_amdgcn_mfma_f32_16x16x32_bf16(
              af[mi][ks], bf[ni][ks], acc[mi][ni], 0, 0, 0);
    __builtin_amdgcn_s_setprio(0);
    // remaining A frags (after half1 in source to ease peak liveness)
#pragma unroll
    for (int mi = 4; mi < 8; mi++) {
      af[mi][0] = *(const bf16x8*)&As[(wm + mi * 16 + col) * 64 + roff0];
      af[mi][1] = *(const bf16x8*)&As[(wm + mi * 16 + col) * 64 + roff1];
    }
    // all our reads from this slot issued above; drain + barrier -> slot free
    asm volatile("s_waitcnt lgkmcnt(0)" ::: "memory");
    __builtin_amdgcn_s_barrier();
    __builtin_amdgcn_sched_barrier(0);
    if (t + 2 < NT) stage(t + 2, slot);
    __builtin_amdgcn_sched_barrier(0);
    // half 2: mi 4..7 (hides the stage issue + part of load latency)
    __builtin_amdgcn_s_setprio(1);
#pragma unroll
    for (int mi = 4; mi < 8; mi++)
#pragma unroll
      for (int ni = 0; ni < 4; ni++)
#pragma unroll
        for (int ks = 0; ks < 2; ks++)
          acc[mi][ni] = __builtin_amdgcn_mfma_f32_16x16x32_bf16(
              af[mi][ks], bf[ni][ks], acc[mi][ni], 0, 0, 0);
    __builtin_amdgcn_s_setprio(0);
    if (t + 1 < NT) {
      if (t + 2 < NT)
        asm volatile("s_waitcnt vmcnt(8)" ::: "memory");  // tile t+1 resident
      else
        asm volatile("s_waitcnt vmcnt(0)" ::: "memory");  // final drain
      __builtin_amdgcn_s_barrier();
      __builtin_amdgcn_sched_barrier(0);
    }
  }

  float* Cpf = (MODE == 3) ? ((float*)Cout + (size_t)ksplit * M * N) : (float*)Cout;
#pragma unroll
  for (int ni = 0; ni < 4; ni++) {
    const int cc = n0 + wn + ni * 16 + col;
    const float bv = (MODE == 3) ? 0.f : bias[cc];
#pragma unroll
    for (int mi = 0; mi < 8; mi++) {
#pragma unroll
      for (int r = 0; r < 4; r++) {
        const int rr = m0 + wm + mi * 16 + quad * 4 + r;
        float v = acc[mi][ni][r] + bv;
        if constexpr (MODE == 2) v = gelu_tanh(v);
        if constexpr (MODE == 3)
          Cpf[(size_t)rr * N + cc] = v;
        else
          ((__bf16*)Cout)[(size_t)rr * N + cc] = (__bf16)v;
      }
    }
  }
}

// ---------------------------------------------------------------------------
// Flash attention (MQA): grid (S/64, H, B), 256 threads (4 waves).
// ---------------------------------------------------------------------------
__global__ __launch_bounds__(256)
void flash_kernel(const __bf16* __restrict__ qkv, const __bf16* __restrict__ vT,
                  __bf16* __restrict__ ctx)
{
  const int qt = blockIdx.x, h = blockIdx.y, b = blockIdx.z;
  const int tid  = threadIdx.x;
  const int lane = tid & 63, wave = tid >> 6;
  const int col  = lane & 15, quad = lane >> 4;
  __shared__ __bf16 Qs[64 * 128];
  __shared__ __bf16 Ks[64 * 128];
  __shared__ __bf16 Vs[128 * 64];   // transposed: [d][key]
  __shared__ __bf16 Ps[4][16 * 64];

#pragma unroll
  for (int p = 0; p < 4; p++) {
    int c = tid + p * 256;
    glds16(qkv + (size_t)(b * 1024 + qt * 64 + (c >> 4)) * 2304 + h * 128 + (c & 15) * 8,
           Qs + c * 8);
  }

  float m_i[4], l_i[4];
  floatx4 o[8] = {};
#pragma unroll
  for (int r = 0; r < 4; r++) { m_i[r] = -1e30f; l_i[r] = 0.f; }

  for (int kt = 0; kt <= qt; kt++) {
    __syncthreads();
#pragma unroll
    for (int p = 0; p < 4; p++) {
      int c = tid + p * 256;
      glds16(qkv + (size_t)(b * 1024 + kt * 64 + (c >> 4)) * 2304 + 2048 + (c & 15) * 8,
             Ks + c * 8);
    }
#pragma unroll
    for (int p = 0; p < 4; p++) {
      int c = tid + p * 256;
      glds16(vT + (size_t)b * 131072 + (size_t)(c >> 3) * 1024 + kt * 64 + (c & 7) * 8,
             Vs + c * 8);
    }
    __syncthreads();

    floatx4 sc[4] = {};
#pragma unroll
    for (int kk = 0; kk < 4; kk++) {
      bf16x8 qa = *(const bf16x8*)&Qs[(wave * 16 + col) * 128 + kk * 32 + quad * 8];
#pragma unroll
      for (int ni = 0; ni < 4; ni++) {
        bf16x8 kb = *(const bf16x8*)&Ks[(ni * 16 + col) * 128 + kk * 32 + quad * 8];
        sc[ni] = __builtin_amdgcn_mfma_f32_16x16x32_bf16(qa, kb, sc[ni], 0, 0, 0);
      }
    }

    const bool diag = (kt == qt);
#pragma unroll
    for (int r = 0; r < 4; r++) {
      const int rowL = wave * 16 + quad * 4 + r;
      float mx = -1e30f;
#pragma unroll
      for (int ni = 0; ni < 4; ni++) {
        float s = sc[ni][r] * 0.08838834764831845f;
        if (diag && (ni * 16 + col) > rowL) s = -1e30f;
        sc[ni][r] = s;
        mx = fmaxf(mx, s);
      }
#pragma unroll
      for (int off = 1; off < 16; off <<= 1) mx = fmaxf(mx, __shfl_xor(mx, off));
      const float mnew = fmaxf(m_i[r], mx);
      const float alpha = __expf(m_i[r] - mnew);
      l_i[r] *= alpha;
      float rsum = 0.f;
#pragma unroll
      for (int ni = 0; ni < 4; ni++) {
        float p = __expf(sc[ni][r] - mnew);
        sc[ni][r] = p;
        rsum += p;
      }
#pragma unroll
      for (int off = 1; off < 16; off <<= 1) rsum += __shfl_xor(rsum, off);
      l_i[r] += rsum;
      m_i[r] = mnew;
#pragma unroll
      for (int nd = 0; nd < 8; nd++) o[nd][r] *= alpha;
    }

    __bf16* Pw = &Ps[wave][0];
#pragma unroll
    for (int r = 0; r < 4; r++)
#pragma unroll
      for (int ni = 0; ni < 4; ni++)
        Pw[(quad * 4 + r) * 64 + ni * 16 + col] = (__bf16)sc[ni][r];

#pragma unroll
    for (int kk = 0; kk < 2; kk++) {
      bf16x8 pa = *(const bf16x8*)&Pw[col * 64 + kk * 32 + quad * 8];
#pragma unroll
      for (int nd = 0; nd < 8; nd++) {
        bf16x8 vb = *(const bf16x8*)&Vs[(nd * 16 + col) * 64 + kk * 32 + quad * 8];
        o[nd] = __builtin_amdgcn_mfma_f32_16x16x32_bf16(pa, vb, o[nd], 0, 0, 0);
      }
    }
  }

#pragma unroll
  for (int r = 0; r < 4; r++) {
    const float inv = 1.f / l_i[r];
    const int row = qt * 64 + wave * 16 + quad * 4 + r;
    const size_t base = (size_t)(b * 1024 + row) * 2048 + h * 128;
#pragma unroll
    for (int nd = 0; nd < 8; nd++)
      ctx[base + nd * 16 + col] = (__bf16)(o[nd][r] * inv);
  }
}

// ---------------------------------------------------------------------------
// Orchestration
// ---------------------------------------------------------------------------
extern "C" void kernel_launch(void* const* d_in, const int* in_sizes, int n_in,
                              void* d_out, int out_size, void* d_ws, size_t ws_size,
                              hipStream_t stream)
{
  (void)in_sizes; (void)n_in; (void)out_size; (void)ws_size;
  const int*   ids = (const int*)d_in[0];
  const int*   pos = (const int*)d_in[1];
  const float* wte = (const float*)d_in[2];
  const float* wpe = (const float*)d_in[3];
  const float* caw = (const float*)d_in[4];
  const float* cab = (const float*)d_in[5];
  const float* cpw = (const float*)d_in[6];
  const float* cpb = (const float*)d_in[7];
  const float* l1w = (const float*)d_in[8];
  const float* l1b = (const float*)d_in[9];
  const float* l2w = (const float*)d_in[10];
  const float* l2b = (const float*)d_in[11];
  const float* fcw = (const float*)d_in[12];
  const float* fcb = (const float*)d_in[13];
  const float* mpw = (const float*)d_in[14];
  const float* mpb = (const float*)d_in[15];
  const float* lfw = (const float*)d_in[16];
  const float* lfb = (const float*)d_in[17];
  float* out = (float*)d_out;

  char* ws = (char*)d_ws;
  float*  resA  = (float*)(ws + 0);           // 16.8 MB
  float*  resB  = (float*)(ws + 16777216);    // 16.8 MB
  __bf16* xb    = (__bf16*)(ws + 33554432);   //  8.4 MB
  __bf16* qkvb  = (__bf16*)(ws + 41943040);   //  9.4 MB
  __bf16* ctxb  = (__bf16*)(ws + 51380224);   //  8.4 MB
  __bf16* vtb   = (__bf16*)(ws + 59768832);   //  0.5 MB
  __bf16* wqkvT = (__bf16*)(ws + 60293120);   //  9.4 MB (per-layer)
  __bf16* wprjT = (__bf16*)(ws + 69730304);   //  8.4 MB (per-layer)
  __bf16* wfcT  = (__bf16*)(ws + 78118912);   // 33.6 MB (per-layer)
  __bf16* wmpT  = (__bf16*)(ws + 111673344);  // 33.6 MB (per-layer)
  // time-shared arena: pq (2x2048x2304 f32 = 37.7MB) | mlp1b (2048x8192 bf16)
  //                    — disjoint live ranges
  char*   arena = ws + 145227776;             // 37.75 MB
  float*  pq    = (float*)arena;
  __bf16* mlp1b = (__bf16*)arena;
  float*  pm    = (float*)(ws + 182976512);   // 4x2048x2048 f32 = 67.1 MB
  // pm is time-shared within a layer: proj partials (x4) -> ln2, then
  // mp partials (x4) -> next ln1 / final ln. Disjoint live ranges.
  // total: 250.1 MB (round-1 proved >= 280.6 MB available)

  const size_t MN  = (size_t)2048 * 2048;   // per-split partial stride (proj/mp)
  const size_t MNq = (size_t)2048 * 2304;   // qkv partial stride

  embed_kernel<<<2048, 256, 0, stream>>>(ids, pos, wte, wpe, resA);

  for (int l = 0; l < 2; l++) {
    // --- ln1: res = h (+ residual); also reduces prev layer's mp partials ---
    if (l == 0)
      ln_red_kernel<<<2048, 256, 0, stream>>>(
          resA, nullptr, nullptr, nullptr, nullptr, nullptr,
          nullptr, xb, nullptr, l1w, l1b);
    else
      ln_red_kernel<<<2048, 256, 0, stream>>>(
          pm, pm + MN, pm + 2 * MN, pm + 3 * MN, mpb, resB,
          resA, xb, nullptr, l1w + 2048, l1b + 2048);

    // --- qkv = x @ c_attn_w + b  (legacy 128^2 split-K x2) ---
    wcvt_kernel<<<dim3(72, 64), 256, 0, stream>>>(caw + (size_t)l * 2048 * 2304,
                                                  wqkvT, 2048, 2304);
    gemm_bt_kernel<3><<<dim3(18, 16, 2), 256, 0, stream>>>(
        xb, wqkvT, nullptr, pq, 2048, 2304, 2048, 1024);
    bias_red_bf16_kernel<<<4608, 256, 0, stream>>>(pq, pq + MNq, cab + l * 2304, qkvb);

    // --- attention ---
    vtr_kernel<<<dim3(4, 32, 2), 256, 0, stream>>>(qkvb, vtb);
    flash_kernel<<<dim3(16, 16, 2), 256, 0, stream>>>(qkvb, vtb, ctxb);

    // --- attn_out = ctx @ c_proj_w + b (256^2 split-K x4 -> pm), fused ln2 ---
    wcvt_kernel<<<dim3(64, 64), 256, 0, stream>>>(cpw + (size_t)l * 2048 * 2048,
                                                  wprjT, 2048, 2048);
    gemm256_kernel<3><<<dim3(8, 8, 4), 512, 0, stream>>>(
        ctxb, wprjT, nullptr, pm, 2048, 2048, 2048, 512);
    ln_red_kernel<<<2048, 256, 0, stream>>>(
        pm, pm + MN, pm + 2 * MN, pm + 3 * MN, cpb + l * 2048, resA,
        resB, xb, nullptr, l2w + l * 2048, l2b + l * 2048);

    // --- mlp1 = gelu(x2 @ fc_w + b)  (256^2, 256 blocks, no split) ---
    wcvt_kernel<<<dim3(256, 64), 256, 0, stream>>>(fcw + (size_t)l * 2048 * 8192,
                                                   wfcT, 2048, 8192);
    gemm256_kernel<2><<<dim3(32, 8, 1), 512, 0, stream>>>(
        xb, wfcT, fcb + l * 8192, mlp1b, 2048, 8192, 2048, 2048);

    // --- mlp = mlp1 @ mp_w + b (256^2 split-K x4), reduced in next LN ---
    wcvt_kernel<<<dim3(64, 256), 256, 0, stream>>>(mpw + (size_t)l * 8192 * 2048,
                                                   wmpT, 8192, 2048);
    gemm256_kernel<3><<<dim3(8, 8, 4), 512, 0, stream>>>(
        mlp1b, wmpT, nullptr, pm, 2048, 2048, 8192, 2048);
  }

  // final: ln(h + residual) = ln(mp_out + resB)
  ln_red_kernel<<<2048, 256, 0, stream>>>(
      pm, pm + MN, pm + 2 * MN, pm + 3 * MN, mpb + 2048, resB,
      nullptr, nullptr, out, lfw, lfb);
}

// Round 2
// 1198.380 us; speedup vs baseline: 1.2082x; 1.0420x over previous
//
#include <hip/hip_runtime.h>
#include <math.h>

// ---------------------------------------------------------------------------
// Santacoder MQA prefill: B=2, S=1024, D=2048, H=16, HD=128, L=2, FF=8192
// R4: (a) qkv moved to the 256^2 pipelined GEMM, MODE 1 (bf16+bias direct,
// no split-K, no bias_red, no pq partials). (b) flash_kernel LDS fully
// XOR-swizzled (Qs/Ks/Vs via pre-swizzled global_load_lds source + swizzled
// reads; Ps swizzled on write and read) - kills the 16-way bank conflicts
// on every ds_read_b128. Legacy 128^2 GEMM and bias_red deleted.
// ---------------------------------------------------------------------------

typedef __bf16 bf16x8 __attribute__((ext_vector_type(8)));
typedef __bf16 bf16x4v __attribute__((ext_vector_type(4)));
typedef float floatx4 __attribute__((ext_vector_type(4)));

typedef const __attribute__((address_space(1))) void* gas_ptr;
typedef __attribute__((address_space(3))) void* las_ptr;

__device__ __forceinline__ void glds16(const __bf16* g, __bf16* l) {
  __builtin_amdgcn_global_load_lds((gas_ptr)g, (las_ptr)l, 16, 0, 0);
}

__device__ __forceinline__ float gelu_tanh(float x) {
  float u = 0.7978845608028654f * (x + 0.044715f * x * x * x);
  return 0.5f * x * (1.f + tanhf(u));
}

// ---------------------------------------------------------------------------
// Embedding: h[t] = wte[ids[t]] + wpe[pos[t]]
// ---------------------------------------------------------------------------
__global__ __launch_bounds__(256)
void embed_kernel(const int* __restrict__ ids, const int* __restrict__ pos,
                  const float* __restrict__ wte, const float* __restrict__ wpe,
                  float* __restrict__ out)
{
  const int t = blockIdx.x;
  const int id = ids[t], pp = pos[t];
  const float4* a = (const float4*)(wte + (size_t)id * 2048);
  const float4* b = (const float4*)(wpe + (size_t)pp * 2048);
  float4* o = (float4*)(out + (size_t)t * 2048);
#pragma unroll
  for (int j = 0; j < 2; j++) {
    int i = threadIdx.x + j * 256;
    float4 x = a[i], y = b[i];
    x.x += y.x; x.y += y.y; x.z += y.z; x.w += y.w;
    o[i] = x;
  }
}

// ---------------------------------------------------------------------------
// Weight convert + transpose: in f32 [K][N] -> out bf16 [N][K]
// ---------------------------------------------------------------------------
__global__ __launch_bounds__(256)
void wcvt_kernel(const float* __restrict__ in, __bf16* __restrict__ out,
                 const int K, const int N)
{
  __shared__ __bf16 tile[32][36];
  const int n0 = blockIdx.x * 32, k0 = blockIdx.y * 32;
  const int t = threadIdx.x;
  const int r = t >> 3, c = (t & 7) * 4;
  const float4 v = *(const float4*)&in[(size_t)(k0 + r) * N + n0 + c];
  tile[r][c + 0] = (__bf16)v.x;
  tile[r][c + 1] = (__bf16)v.y;
  tile[r][c + 2] = (__bf16)v.z;
  tile[r][c + 3] = (__bf16)v.w;
  __syncthreads();
  bf16x4v w;
  w.x = tile[c + 0][r]; w.y = tile[c + 1][r];
  w.z = tile[c + 2][r]; w.w = tile[c + 3][r];
  *(bf16x4v*)&out[(size_t)(n0 + r) * K + k0 + c] = w;
}

// ---------------------------------------------------------------------------
// V transpose: qkv[:, 2176:2304] bf16 -> vT [B][128][1024]
// ---------------------------------------------------------------------------
__global__ __launch_bounds__(256)
void vtr_kernel(const __bf16* __restrict__ qkvb, __bf16* __restrict__ vT)
{
  __shared__ __bf16 tile[32][36];
  const int d0 = blockIdx.x * 32, s0 = blockIdx.y * 32, b = blockIdx.z;
  const int t = threadIdx.x;
  const int r = t >> 3, c = (t & 7) * 4;
  bf16x4v v = *(const bf16x4v*)&qkvb[(size_t)(b * 1024 + s0 + r) * 2304 + 2176 + d0 + c];
  tile[r][c + 0] = v.x; tile[r][c + 1] = v.y;
  tile[r][c + 2] = v.z; tile[r][c + 3] = v.w;
  __syncthreads();
  bf16x4v w;
  w.x = tile[c + 0][r]; w.y = tile[c + 1][r];
  w.z = tile[c + 2][r]; w.w = tile[c + 3][r];
  *(bf16x4v*)&vT[(size_t)b * 131072 + (size_t)(d0 + r) * 1024 + s0 + c] = w;
}

// ---------------------------------------------------------------------------
// Fused partial-sum reduce + bias + residual-add + LayerNorm.
// x = p0 [+p1 +p2 +p3] [+cbias] [+resid]; res_out=x (opt); LN(x) -> out_b/out_f
// ---------------------------------------------------------------------------
__global__ __launch_bounds__(256)
void ln_red_kernel(const float* __restrict__ p0, const float* __restrict__ p1,
                   const float* __restrict__ p2, const float* __restrict__ p3,
                   const float* __restrict__ cbias, const float* __restrict__ resid,
                   float* __restrict__ res_out, __bf16* __restrict__ out_b,
                   float* __restrict__ out_f,
                   const float* __restrict__ gw, const float* __restrict__ gb)
{
  const int row = blockIdx.x;
  const int tid = threadIdx.x;
  const size_t base = (size_t)row * 2048;
  float4 v[2];
  float s = 0.f, sq = 0.f;
#pragma unroll
  for (int j = 0; j < 2; j++) {
    const int idx = tid + j * 256;
    float4 a = ((const float4*)(p0 + base))[idx];
    if (p1) { float4 t = ((const float4*)(p1 + base))[idx];
      a.x += t.x; a.y += t.y; a.z += t.z; a.w += t.w; }
    if (p2) { float4 t = ((const float4*)(p2 + base))[idx];
      a.x += t.x; a.y += t.y; a.z += t.z; a.w += t.w; }
    if (p3) { float4 t = ((const float4*)(p3 + base))[idx];
      a.x += t.x; a.y += t.y; a.z += t.z; a.w += t.w; }
    if (cbias) { float4 t = ((const float4*)cbias)[idx];
      a.x += t.x; a.y += t.y; a.z += t.z; a.w += t.w; }
    if (resid) { float4 t = ((const float4*)(resid + base))[idx];
      a.x += t.x; a.y += t.y; a.z += t.z; a.w += t.w; }
    if (res_out) ((float4*)(res_out + base))[idx] = a;
    v[j] = a;
    s  += a.x + a.y + a.z + a.w;
    sq += a.x * a.x + a.y * a.y + a.z * a.z + a.w * a.w;
  }
  __shared__ float rs[4], rq[4];
  __shared__ float sh_stats[2];
#pragma unroll
  for (int off = 32; off > 0; off >>= 1) {
    s  += __shfl_down(s, off);
    sq += __shfl_down(sq, off);
  }
  const int lane = tid & 63, wave = tid >> 6;
  if (lane == 0) { rs[wave] = s; rq[wave] = sq; }
  __syncthreads();
  if (tid == 0) {
    float S = rs[0] + rs[1] + rs[2] + rs[3];
    float Q = rq[0] + rq[1] + rq[2] + rq[3];
    float mean = S * (1.f / 2048.f);
    float var  = Q * (1.f / 2048.f) - mean * mean;
    sh_stats[0] = mean;
    sh_stats[1] = rsqrtf(var + 1e-5f);
  }
  __syncthreads();
  const float mean = sh_stats[0], rstd = sh_stats[1];
#pragma unroll
  for (int j = 0; j < 2; j++) {
    const int idx = tid + j * 256;
    float4 a = v[j];
    float4 g4 = ((const float4*)gw)[idx];
    float4 b4 = ((const float4*)gb)[idx];
    float y0 = (a.x - mean) * rstd * g4.x + b4.x;
    float y1 = (a.y - mean) * rstd * g4.y + b4.y;
    float y2 = (a.z - mean) * rstd * g4.z + b4.z;
    float y3 = (a.w - mean) * rstd * g4.w + b4.w;
    if (out_b) {
      bf16x4v w;
      w.x = (__bf16)y0; w.y = (__bf16)y1; w.z = (__bf16)y2; w.w = (__bf16)y3;
      *(bf16x4v*)&out_b[base + (size_t)idx * 4] = w;
    }
    if (out_f) {
      float4 w; w.x = y0; w.y = y1; w.z = y2; w.w = y3;
      ((float4*)(out_f + base))[idx] = w;
    }
  }
}

// ---------------------------------------------------------------------------
// 256x256 tile GEMM, BK=64, 512 threads (2M x 4N waves), double-buffered
// 128 KiB LDS, counted-vmcnt pipeline (T3+T4), XOR-swizzled LDS (T2, rule
// #21: linear glds dest + inverse-swizzled GLOBAL source + swizzled read),
// setprio around MFMA clusters (T5). 1 block/CU (LDS-pinned).
//   MODE 1: bf16 out + bias; MODE 2: bf16 + bias + gelu;
//   MODE 3: f32 partial (no bias) at split*M*N.
// Requires: M%256==0, N%256==0, Kper%64==0, Kper/64 >= 2.
// Ledger: prologue stages tiles 0,1 -> vmcnt(8)+bar (tile0 resident).
// iter t: read frags from slot t&1 -> MFMA half1 -> lgkmcnt(0)+bar (slot
// free) -> stage tile t+2 into slot -> MFMA half2 -> vmcnt(8)+bar (tile t+1
// resident). Tail: no stage; vmcnt(0) before last-tile iter.
// ---------------------------------------------------------------------------
template<int MODE>
__global__ __launch_bounds__(512, 2)
void gemm256_kernel(const __bf16* __restrict__ A, const __bf16* __restrict__ Bt,
                    const float* __restrict__ bias, void* __restrict__ Cout,
                    const int M, const int N, const int K, const int Kper)
{
  __shared__ alignas(16) __bf16 sm[65536];  // [slot][A(16384)|B(16384)] = 128 KiB
  const int tid  = threadIdx.x;
  const int lane = tid & 63;
  const int wave = tid >> 6;
  const int col  = lane & 15;
  const int quad = lane >> 4;
  const int wm = (wave >> 2) * 128;   // wave row-offset (2 waves in M)
  const int wn = (wave & 3) * 64;     // wave col-offset (4 waves in N)
  const int m0 = blockIdx.y * 256;
  const int n0 = blockIdx.x * 256;
  const int ksplit = blockIdx.z;

  const __bf16* Ag = A  + (size_t)m0 * K + (size_t)ksplit * Kper;
  const __bf16* Bg = Bt + (size_t)n0 * K + (size_t)ksplit * Kper;

  // staging: thread tid covers LDS 16B slot (row = i*64 + tid>>3,
  // slot8 = tid&7). Source column pre-swizzled: c8 = (tid&7) ^ (row&7).
  const int sr = tid >> 3;                       // 0..63 rows per issue
  const int sc = (((tid & 7) ^ (sr & 7)) * 8);   // swizzled source col (elems)
  const int ld = tid * 8;                        // linear LDS dest (elems)

  // read side: frag at k-slot k8=(ks<<2)|quad lives at LDS slot8 k8^(row&7);
  // row&7 == col&7 for every fragment row (wm,mi*16,wn,ni*16 are 0 mod 8).
  const int roff0 = (((0 | quad) ^ (col & 7)) * 8);
  const int roff1 = (((4 | quad) ^ (col & 7)) * 8);

  const int NT = Kper / 64;

  auto stage = [&](int t, int slot) {
    __bf16* dA = sm + slot * 32768;
    __bf16* dB = dA + 16384;
    const __bf16* gA = Ag + t * 64;
    const __bf16* gB = Bg + t * 64;
#pragma unroll
    for (int i = 0; i < 4; i++)
      glds16(gA + (size_t)(i * 64 + sr) * K + sc, dA + i * 4096 + ld);
#pragma unroll
    for (int i = 0; i < 4; i++)
      glds16(gB + (size_t)(i * 64 + sr) * K + sc, dB + i * 4096 + ld);
  };

  floatx4 acc[8][4] = {};

  // prologue
  stage(0, 0);
  stage(1, 1);
  asm volatile("s_waitcnt vmcnt(8)" ::: "memory");
  __builtin_amdgcn_s_barrier();
  __builtin_amdgcn_sched_barrier(0);

  for (int t = 0; t < NT; t++) {
    const int slot = t & 1;
    const __bf16* As = sm + slot * 32768;
    const __bf16* Bs = As + 16384;
    bf16x8 af[8][2], bf[4][2];
#pragma unroll
    for (int ni = 0; ni < 4; ni++) {
      bf[ni][0] = *(const bf16x8*)&Bs[(wn + ni * 16 + col) * 64 + roff0];
      bf[ni][1] = *(const bf16x8*)&Bs[(wn + ni * 16 + col) * 64 + roff1];
    }
#pragma unroll
    for (int mi = 0; mi < 4; mi++) {
      af[mi][0] = *(const bf16x8*)&As[(wm + mi * 16 + col) * 64 + roff0];
      af[mi][1] = *(const bf16x8*)&As[(wm + mi * 16 + col) * 64 + roff1];
    }
    // half 1: mi 0..3 (compiler inserts fine-grained lgkmcnt for frag deps)
    __builtin_amdgcn_s_setprio(1);
#pragma unroll
    for (int mi = 0; mi < 4; mi++)
#pragma unroll
      for (int ni = 0; ni < 4; ni++)
#pragma unroll
        for (int ks = 0; ks < 2; ks++)
          acc[mi][ni] = __builtin_amdgcn_mfma_f32_16x16x32_bf16(
              af[mi][ks], bf[ni][ks], acc[mi][ni], 0, 0, 0);
    __builtin_amdgcn_s_setprio(0);
    // remaining A frags (after half1 in source to ease peak liveness)
#pragma unroll
    for (int mi = 4; mi < 8; mi++) {
      af[mi][0] = *(const bf16x8*)&As[(wm + mi * 16 + col) * 64 + roff0];
      af[mi][1] = *(const bf16x8*)&As[(wm + mi * 16 + col) * 64 + roff1];
    }
    // all our reads from this slot issued above; drain + barrier -> slot free
    asm volatile("s_waitcnt lgkmcnt(0)" ::: "memory");
    __builtin_amdgcn_s_barrier();
    __builtin_amdgcn_sched_barrier(0);
    if (t + 2 < NT) stage(t + 2, slot);
    __builtin_amdgcn_sched_barrier(0);
    // half 2: mi 4..7 (hides the stage issue + part of load latency)
    __builtin_amdgcn_s_setprio(1);
#pragma unroll
    for (int mi = 4; mi < 8; mi++)
#pragma unroll
      for (int ni = 0; ni < 4; ni++)
#pragma unroll
        for (int ks = 0; ks < 2; ks++)
          acc[mi][ni] = __builtin_amdgcn_mfma_f32_16x16x32_bf16(
              af[mi][ks], bf[ni][ks], acc[mi][ni], 0, 0, 0);
    __builtin_amdgcn_s_setprio(0);
    if (t + 1 < NT) {
      if (t + 2 < NT)
        asm volatile("s_waitcnt vmcnt(8)" ::: "memory");  // tile t+1 resident
      else
        asm volatile("s_waitcnt vmcnt(0)" ::: "memory");  // final drain
      __builtin_amdgcn_s_barrier();
      __builtin_amdgcn_sched_barrier(0);
    }
  }

  float* Cpf = (MODE == 3) ? ((float*)Cout + (size_t)ksplit * M * N) : (float*)Cout;
#pragma unroll
  for (int ni = 0; ni < 4; ni++) {
    const int cc = n0 + wn + ni * 16 + col;
    const float bv = (MODE == 3) ? 0.f : bias[cc];
#pragma unroll
    for (int mi = 0; mi < 8; mi++) {
#pragma unroll
      for (int r = 0; r < 4; r++) {
        const int rr = m0 + wm + mi * 16 + quad * 4 + r;
        float v = acc[mi][ni][r] + bv;
        if constexpr (MODE == 2) v = gelu_tanh(v);
        if constexpr (MODE == 3)
          Cpf[(size_t)rr * N + cc] = v;
        else
          ((__bf16*)Cout)[(size_t)rr * N + cc] = (__bf16)v;
      }
    }
  }
}

// ---------------------------------------------------------------------------
// Flash attention (MQA): grid (S/64, H, B), 256 threads (4 waves).
// R4: all LDS buffers XOR-swizzled. Convention: within each row, the logical
// 16B-group g is stored at slot g^(row&7) (low 3 bits). Staging keeps the
// glds dest lane-linear and pre-swizzles the GLOBAL source (rule #21); reads
// apply the same XOR. Ps is reg-written, so swizzle is applied on the write
// address and on the b128 read.
// ---------------------------------------------------------------------------
__global__ __launch_bounds__(256)
void flash_kernel(const __bf16* __restrict__ qkv, const __bf16* __restrict__ vT,
                  __bf16* __restrict__ ctx)
{
  const int qt = blockIdx.x, h = blockIdx.y, b = blockIdx.z;
  const int tid  = threadIdx.x;
  const int lane = tid & 63, wave = tid >> 6;
  const int col  = lane & 15, quad = lane >> 4;
  __shared__ __bf16 Qs[64 * 128];
  __shared__ __bf16 Ks[64 * 128];
  __shared__ __bf16 Vs[128 * 64];   // transposed: [d][key]
  __shared__ __bf16 Ps[4][16 * 64];

  // Q stage: row = c>>4, dest slot s = c&15; fetch logical group
  // g = (s&8) | ((s^row)&7) from global.
#pragma unroll
  for (int p = 0; p < 4; p++) {
    int c = tid + p * 256;
    int row = c >> 4, s = c & 15;
    int g = (s & 8) | ((s ^ row) & 7);
    glds16(qkv + (size_t)(b * 1024 + qt * 64 + row) * 2304 + h * 128 + g * 8,
           Qs + c * 8);
  }

  float m_i[4], l_i[4];
  floatx4 o[8] = {};
#pragma unroll
  for (int r = 0; r < 4; r++) { m_i[r] = -1e30f; l_i[r] = 0.f; }

  for (int kt = 0; kt <= qt; kt++) {
    __syncthreads();
#pragma unroll
    for (int p = 0; p < 4; p++) {
      int c = tid + p * 256;
      int row = c >> 4, s = c & 15;
      int g = (s & 8) | ((s ^ row) & 7);
      glds16(qkv + (size_t)(b * 1024 + kt * 64 + row) * 2304 + 2048 + g * 8,
             Ks + c * 8);
    }
#pragma unroll
    for (int p = 0; p < 4; p++) {
      int c = tid + p * 256;
      int row = c >> 3, s = c & 7;
      int g = (s ^ row) & 7;
      glds16(vT + (size_t)b * 131072 + (size_t)row * 1024 + kt * 64 + g * 8,
             Vs + c * 8);
    }
    __syncthreads();

    floatx4 sc[4] = {};
#pragma unroll
    for (int kk = 0; kk < 4; kk++) {
      const int lg = kk * 4 + quad;
      const int qrow = wave * 16 + col;
      bf16x8 qa = *(const bf16x8*)&Qs[qrow * 128 + (((lg & 8) | ((lg ^ qrow) & 7)) * 8)];
#pragma unroll
      for (int ni = 0; ni < 4; ni++) {
        const int krow = ni * 16 + col;
        bf16x8 kb = *(const bf16x8*)&Ks[krow * 128 + (((lg & 8) | ((lg ^ krow) & 7)) * 8)];
        sc[ni] = __builtin_amdgcn_mfma_f32_16x16x32_bf16(qa, kb, sc[ni], 0, 0, 0);
      }
    }

    const bool diag = (kt == qt);
#pragma unroll
    for (int r = 0; r < 4; r++) {
      const int rowL = wave * 16 + quad * 4 + r;
      float mx = -1e30f;
#pragma unroll
      for (int ni = 0; ni < 4; ni++) {
        float s = sc[ni][r] * 0.08838834764831845f;
        if (diag && (ni * 16 + col) > rowL) s = -1e30f;
        sc[ni][r] = s;
        mx = fmaxf(mx, s);
      }
#pragma unroll
      for (int off = 1; off < 16; off <<= 1) mx = fmaxf(mx, __shfl_xor(mx, off));
      const float mnew = fmaxf(m_i[r], mx);
      const float alpha = __expf(m_i[r] - mnew);
      l_i[r] *= alpha;
      float rsum = 0.f;
#pragma unroll
      for (int ni = 0; ni < 4; ni++) {
        float p = __expf(sc[ni][r] - mnew);
        sc[ni][r] = p;
        rsum += p;
      }
#pragma unroll
      for (int off = 1; off < 16; off <<= 1) rsum += __shfl_xor(rsum, off);
      l_i[r] += rsum;
      m_i[r] = mnew;
#pragma unroll
      for (int nd = 0; nd < 8; nd++) o[nd][r] *= alpha;
    }

    __bf16* Pw = &Ps[wave][0];
#pragma unroll
    for (int r = 0; r < 4; r++) {
      const int pr = quad * 4 + r;
#pragma unroll
      for (int ni = 0; ni < 4; ni++) {
        const int pc = ni * 16 + col;
        const int pcs = (pc & 7) | ((((pc >> 3) ^ pr) & 7) << 3);
        Pw[pr * 64 + pcs] = (__bf16)sc[ni][r];
      }
    }

#pragma unroll
    for (int kk = 0; kk < 2; kk++) {
      const int lg = kk * 4 + quad;          // 0..7
      bf16x8 pa = *(const bf16x8*)&Pw[col * 64 + (((lg ^ col) & 7) * 8)];
#pragma unroll
      for (int nd = 0; nd < 8; nd++) {
        const int vr = nd * 16 + col;
        bf16x8 vb = *(const bf16x8*)&Vs[vr * 64 + (((lg ^ vr) & 7) * 8)];
        o[nd] = __builtin_amdgcn_mfma_f32_16x16x32_bf16(pa, vb, o[nd], 0, 0, 0);
      }
    }
  }

#pragma unroll
  for (int r = 0; r < 4; r++) {
    const float inv = 1.f / l_i[r];
    const int row = qt * 64 + wave * 16 + quad * 4 + r;
    const size_t base = (size_t)(b * 1024 + row) * 2048 + h * 128;
#pragma unroll
    for (int nd = 0; nd < 8; nd++)
      ctx[base + nd * 16 + col] = (__bf16)(o[nd][r] * inv);
  }
}

// ---------------------------------------------------------------------------
// Orchestration
// ---------------------------------------------------------------------------
extern "C" void kernel_launch(void* const* d_in, const int* in_sizes, int n_in,
                              void* d_out, int out_size, void* d_ws, size_t ws_size,
                              hipStream_t stream)
{
  (void)in_sizes; (void)n_in; (void)out_size; (void)ws_size;
  const int*   ids = (const int*)d_in[0];
  const int*   pos = (const int*)d_in[1];
  const float* wte = (const float*)d_in[2];
  const float* wpe = (const float*)d_in[3];
  const float* caw = (const float*)d_in[4];
  const float* cab = (const float*)d_in[5];
  const float* cpw = (const float*)d_in[6];
  const float* cpb = (const float*)d_in[7];
  const float* l1w = (const float*)d_in[8];
  const float* l1b = (const float*)d_in[9];
  const float* l2w = (const float*)d_in[10];
  const float* l2b = (const float*)d_in[11];
  const float* fcw = (const float*)d_in[12];
  const float* fcb = (const float*)d_in[13];
  const float* mpw = (const float*)d_in[14];
  const float* mpb = (const float*)d_in[15];
  const float* lfw = (const float*)d_in[16];
  const float* lfb = (const float*)d_in[17];
  float* out = (float*)d_out;

  char* ws = (char*)d_ws;
  float*  resA  = (float*)(ws + 0);           // 16.8 MB
  float*  resB  = (float*)(ws + 16777216);    // 16.8 MB
  __bf16* xb    = (__bf16*)(ws + 33554432);   //  8.4 MB
  __bf16* qkvb  = (__bf16*)(ws + 41943040);   //  9.4 MB
  __bf16* ctxb  = (__bf16*)(ws + 51380224);   //  8.4 MB
  __bf16* vtb   = (__bf16*)(ws + 59768832);   //  0.5 MB
  __bf16* wqkvT = (__bf16*)(ws + 60293120);   //  9.4 MB (per-layer)
  __bf16* wprjT = (__bf16*)(ws + 69730304);   //  8.4 MB (per-layer)
  __bf16* wfcT  = (__bf16*)(ws + 78118912);   // 33.6 MB (per-layer)
  __bf16* wmpT  = (__bf16*)(ws + 111673344);  // 33.6 MB (per-layer)
  // arena: mlp1b (2048x8192 bf16 = 33.6MB)
  char*   arena = ws + 145227776;             // 37.75 MB
  __bf16* mlp1b = (__bf16*)arena;
  float*  pm    = (float*)(ws + 182976512);   // 4x2048x2048 f32 = 67.1 MB
  // pm is time-shared within a layer: proj partials (x4) -> ln2, then
  // mp partials (x4) -> next ln1 / final ln. Disjoint live ranges.

  const size_t MN  = (size_t)2048 * 2048;   // per-split partial stride (proj/mp)

  embed_kernel<<<2048, 256, 0, stream>>>(ids, pos, wte, wpe, resA);

  for (int l = 0; l < 2; l++) {
    // --- ln1: res = h (+ residual); also reduces prev layer's mp partials ---
    if (l == 0)
      ln_red_kernel<<<2048, 256, 0, stream>>>(
          resA, nullptr, nullptr, nullptr, nullptr, nullptr,
          nullptr, xb, nullptr, l1w, l1b);
    else
      ln_red_kernel<<<2048, 256, 0, stream>>>(
          pm, pm + MN, pm + 2 * MN, pm + 3 * MN, mpb, resB,
          resA, xb, nullptr, l1w + 2048, l1b + 2048);

    // --- qkv = x @ c_attn_w + b  (256^2 MODE 1, bf16+bias direct) ---
    wcvt_kernel<<<dim3(72, 64), 256, 0, stream>>>(caw + (size_t)l * 2048 * 2304,
                                                  wqkvT, 2048, 2304);
    gemm256_kernel<1><<<dim3(9, 8, 1), 512, 0, stream>>>(
        xb, wqkvT, cab + l * 2304, qkvb, 2048, 2304, 2048, 2048);

    // --- attention ---
    vtr_kernel<<<dim3(4, 32, 2), 256, 0, stream>>>(qkvb, vtb);
    flash_kernel<<<dim3(16, 16, 2), 256, 0, stream>>>(qkvb, vtb, ctxb);

    // --- attn_out = ctx @ c_proj_w + b (256^2 split-K x4 -> pm), fused ln2 ---
    wcvt_kernel<<<dim3(64, 64), 256, 0, stream>>>(cpw + (size_t)l * 2048 * 2048,
                                                  wprjT, 2048, 2048);
    gemm256_kernel<3><<<dim3(8, 8, 4), 512, 0, stream>>>(
        ctxb, wprjT, nullptr, pm, 2048, 2048, 2048, 512);
    ln_red_kernel<<<2048, 256, 0, stream>>>(
        pm, pm + MN, pm + 2 * MN, pm + 3 * MN, cpb + l * 2048, resA,
        resB, xb, nullptr, l2w + l * 2048, l2b + l * 2048);

    // --- mlp1 = gelu(x2 @ fc_w + b)  (256^2, 256 blocks, no split) ---
    wcvt_kernel<<<dim3(256, 64), 256, 0, stream>>>(fcw + (size_t)l * 2048 * 8192,
                                                   wfcT, 2048, 8192);
    gemm256_kernel<2><<<dim3(32, 8, 1), 512, 0, stream>>>(
        xb, wfcT, fcb + l * 8192, mlp1b, 2048, 8192, 2048, 2048);

    // --- mlp = mlp1 @ mp_w + b (256^2 split-K x4), reduced in next LN ---
    wcvt_kernel<<<dim3(64, 256), 256, 0, stream>>>(mpw + (size_t)l * 8192 * 2048,
                                                   wmpT, 8192, 2048);
    gemm256_kernel<3><<<dim3(8, 8, 4), 512, 0, stream>>>(
        mlp1b, wmpT, nullptr, pm, 2048, 2048, 8192, 2048);
  }

  // final: ln(h + residual) = ln(mp_out + resB)
  ln_red_kernel<<<2048, 256, 0, stream>>>(
      pm, pm + MN, pm + 2 * MN, pm + 3 * MN, mpb + 2048, resB,
      nullptr, nullptr, out, lfw, lfb);
}